// Round 1
// baseline (707.824 us; speedup 1.0000x reference)
//
#include <hip/hip_runtime.h>
#include <hip/hip_bf16.h>

#define H 4
#define C 64
#define D 256
#define NEG_SLOPE 0.2f

// ---------------- CSR build ----------------
__global__ void count_kernel(const int* __restrict__ ei, int E, int N, int* __restrict__ counts) {
    int i = blockIdx.x * blockDim.x + threadIdx.x;
    if (i >= E + N) return;
    int d = (i < E) ? ei[E + i] : (i - E);
    atomicAdd(&counts[d], 1);
}

__global__ __launch_bounds__(1024) void prefix_scan(const int* __restrict__ counts,
                                                    int* __restrict__ row_ptr, int N) {
    __shared__ int buf[1024];
    __shared__ int carry_s;
    int tid = threadIdx.x;
    if (tid == 0) carry_s = 0;
    __syncthreads();
    for (int base = 0; base < N; base += 1024) {
        int idx = base + tid;
        int v = (idx < N) ? counts[idx] : 0;
        buf[tid] = v;
        __syncthreads();
        for (int offs = 1; offs < 1024; offs <<= 1) {
            int t = (tid >= offs) ? buf[tid - offs] : 0;
            __syncthreads();
            buf[tid] += t;
            __syncthreads();
        }
        int carry = carry_s;
        int incl = buf[tid];
        if (idx < N) row_ptr[idx] = carry + incl - v;
        __syncthreads();
        if (tid == 1023) carry_s = carry + incl;
        __syncthreads();
    }
    if (tid == 0) row_ptr[N] = carry_s;
}

__global__ void copy_cursor(const int* __restrict__ row_ptr, int* __restrict__ cursor, int N) {
    int i = blockIdx.x * blockDim.x + threadIdx.x;
    if (i < N) cursor[i] = row_ptr[i];
}

__global__ void scatter_kernel(const int* __restrict__ ei, int E, int N,
                               int* __restrict__ cursor, int* __restrict__ csr_src) {
    int i = blockIdx.x * blockDim.x + threadIdx.x;
    if (i >= E + N) return;
    int s, d;
    if (i < E) { s = ei[i]; d = ei[E + i]; }
    else       { s = d = i - E; }
    int pos = atomicAdd(&cursor[d], 1);
    csr_src[pos] = s;
}

// ---------------- fp32 tiled GEMM: C[M,256] = A[M,256] @ W[256,256] ----------------
#define BM 64
#define BN 64
#define BK 16
__global__ __launch_bounds__(256) void gemm_f32(const float* __restrict__ A,
                                                const float* __restrict__ W,
                                                float* __restrict__ Cout, int M) {
    __shared__ float As[BK][BM + 4];   // +4 pad: conflict-free & keeps float4 alignment (68*4=272=16*17)
    __shared__ float Bs[BK][BN];
    int row0 = blockIdx.x * BM;
    int col0 = blockIdx.y * BN;
    int tid = threadIdx.x;
    int tx = tid & 15, ty = tid >> 4;
    float acc[4][4] = {};
    int ar = tid >> 2;            // 0..63: row within A tile
    int ac = (tid & 3) * 4;       // k offset 0,4,8,12
    int br = tid >> 4;            // 0..15: k row of B tile
    int bc = (tid & 15) * 4;      // col offset
    for (int k0 = 0; k0 < D; k0 += BK) {
        float4 av;
        int gr = row0 + ar;
        if (gr < M) av = *(const float4*)&A[gr * D + k0 + ac];
        else        av = make_float4(0.f, 0.f, 0.f, 0.f);
        As[ac + 0][ar] = av.x;
        As[ac + 1][ar] = av.y;
        As[ac + 2][ar] = av.z;
        As[ac + 3][ar] = av.w;
        *(float4*)&Bs[br][bc] = *(const float4*)&W[(k0 + br) * D + col0 + bc];
        __syncthreads();
        #pragma unroll
        for (int k = 0; k < BK; k++) {
            float4 a4 = *(const float4*)&As[k][ty * 4];
            float4 b4 = *(const float4*)&Bs[k][tx * 4];
            float aa[4] = {a4.x, a4.y, a4.z, a4.w};
            float bb[4] = {b4.x, b4.y, b4.z, b4.w};
            #pragma unroll
            for (int i = 0; i < 4; i++)
                #pragma unroll
                for (int j = 0; j < 4; j++)
                    acc[i][j] += aa[i] * bb[j];
        }
        __syncthreads();
    }
    #pragma unroll
    for (int i = 0; i < 4; i++) {
        int gr = row0 + ty * 4 + i;
        if (gr < M) {
            float4 v = make_float4(acc[i][0], acc[i][1], acc[i][2], acc[i][3]);
            *(float4*)&Cout[gr * D + col0 + tx * 4] = v;
        }
    }
}

// ---------------- per-node attention scores ----------------
__global__ __launch_bounds__(256) void attn_scores(const float* __restrict__ hp,
                                                   const float* __restrict__ asrc,
                                                   const float* __restrict__ adst,
                                                   float* __restrict__ out_s,
                                                   float* __restrict__ out_d, int N) {
    int wid = (int)((blockIdx.x * blockDim.x + threadIdx.x) >> 6);
    int lane = threadIdx.x & 63;
    if (wid >= N) return;
    #pragma unroll
    for (int h = 0; h < H; h++) {
        float v = hp[wid * D + h * C + lane];
        float ps = v * asrc[h * C + lane];
        float pd = v * adst[h * C + lane];
        #pragma unroll
        for (int o = 32; o; o >>= 1) {
            ps += __shfl_xor(ps, o);
            pd += __shfl_xor(pd, o);
        }
        if (lane == 0) {
            out_s[wid * H + h] = ps;
            out_d[wid * H + h] = pd;
        }
    }
}

// ---------------- GAT aggregation: one block per dst node, one wave per head ----------------
__global__ __launch_bounds__(256) void gat_aggregate(const float* __restrict__ hp,
                                                     const float* __restrict__ as_,
                                                     const float* __restrict__ ad_,
                                                     const int* __restrict__ row_ptr,
                                                     const int* __restrict__ csr_src,
                                                     const float* __restrict__ bias,
                                                     float* __restrict__ hout, int N) {
    int d = blockIdx.x;
    int h = threadIdx.x >> 6;
    int lane = threadIdx.x & 63;
    int r0 = row_ptr[d], r1 = row_ptr[d + 1];
    int deg = r1 - r0;
    float adv = ad_[d * H + h];

    // pass 1: max logit
    float m = -1e30f;
    for (int i = lane; i < deg; i += 64) {
        int s = csr_src[r0 + i];
        float e = as_[s * H + h] + adv;
        e = e > 0.f ? e : NEG_SLOPE * e;
        m = fmaxf(m, e);
    }
    #pragma unroll
    for (int o = 32; o; o >>= 1) m = fmaxf(m, __shfl_xor(m, o));

    // pass 2: sum of exp
    float ssum = 0.f;
    for (int i = lane; i < deg; i += 64) {
        int s = csr_src[r0 + i];
        float e = as_[s * H + h] + adv;
        e = e > 0.f ? e : NEG_SLOPE * e;
        ssum += __expf(e - m);
    }
    #pragma unroll
    for (int o = 32; o; o >>= 1) ssum += __shfl_xor(ssum, o);
    float inv = 1.0f / ssum;

    // pass 3: weighted accumulate (lane = channel)
    float acc = 0.f;
    for (int i = 0; i < deg; i++) {
        int s = csr_src[r0 + i];
        float e = as_[s * H + h] + adv;
        e = e > 0.f ? e : NEG_SLOPE * e;
        float alpha = __expf(e - m) * inv;
        acc += alpha * hp[s * D + h * C + lane];
    }
    float v = acc + bias[h * C + lane];
    v = v > 0.f ? v : (__expf(v) - 1.0f);   // ELU
    hout[d * D + h * C + lane] = v;
}

// ---------------- pooling + output head ----------------
__global__ __launch_bounds__(256) void col_sum(const float* __restrict__ hin,
                                               float* __restrict__ g, int N, int rows_per_blk) {
    int c = threadIdx.x;
    int r0 = blockIdx.x * rows_per_blk;
    int r1 = min(r0 + rows_per_blk, N);
    float acc = 0.f;
    for (int r = r0; r < r1; r++) acc += hin[r * D + c];
    atomicAdd(&g[c], acc);
}

__global__ __launch_bounds__(256) void final_kernel(const float* __restrict__ g,
                                                    const float* __restrict__ Wout,
                                                    const float* __restrict__ bout,
                                                    float* __restrict__ out, float invN) {
    int j = threadIdx.x;
    float acc = 0.f;
    for (int i = 0; i < D; i++) acc += g[i] * Wout[i * D + j];
    out[j] = acc * invN + bout[j];
}

extern "C" void kernel_launch(void* const* d_in, const int* in_sizes, int n_in,
                              void* d_out, int out_size, void* d_ws, size_t ws_size,
                              hipStream_t stream) {
    const float* x       = (const float*)d_in[0];
    const int*   ei      = (const int*)d_in[1];
    const float* Ws      = (const float*)d_in[2];
    const float* att_src = (const float*)d_in[3];
    const float* att_dst = (const float*)d_in[4];
    const float* biases  = (const float*)d_in[5];
    const float* Wout    = (const float*)d_in[6];
    const float* bout    = (const float*)d_in[7];
    float* out = (float*)d_out;

    int N = in_sizes[0] / D;          // 20000
    int E = in_sizes[1] / 2;          // 320000
    int L = in_sizes[2] / (D * D);    // 4
    int Etot = E + N;

    char* ws = (char*)d_ws;
    size_t off = 0;
    auto alloc = [&](size_t bytes) -> void* {
        void* p = ws + off;
        off = (off + bytes + 255) & ~(size_t)255;
        return p;
    };
    float* bufA    = (float*)alloc((size_t)N * D * 4);
    float* bufB    = (float*)alloc((size_t)N * D * 4);
    float* a_s     = (float*)alloc((size_t)N * H * 4);
    float* a_d     = (float*)alloc((size_t)N * H * 4);
    float* g       = (float*)alloc(D * 4);
    int*   counts  = (int*)alloc((size_t)N * 4);
    int*   row_ptr = (int*)alloc((size_t)(N + 1) * 4);
    int*   cursor  = (int*)alloc((size_t)N * 4);
    int*   csr_src = (int*)alloc((size_t)Etot * 4);
    if (off > ws_size) return;  // workspace too small -> loud failure

    // ---- CSR build (per call; cheap) ----
    hipMemsetAsync(counts, 0, (size_t)N * 4, stream);
    int thr = 256;
    count_kernel<<<(Etot + thr - 1) / thr, thr, 0, stream>>>(ei, E, N, counts);
    prefix_scan<<<1, 1024, 0, stream>>>(counts, row_ptr, N);
    copy_cursor<<<(N + thr - 1) / thr, thr, 0, stream>>>(row_ptr, cursor, N);
    scatter_kernel<<<(Etot + thr - 1) / thr, thr, 0, stream>>>(ei, E, N, cursor, csr_src);

    // ---- layers ----
    dim3 ggrid((N + BM - 1) / BM, D / BN);
    int score_blocks = (N * 64 + 255) / 256;
    for (int l = 0; l < L; l++) {
        const float* hin = (l == 0) ? x : bufA;
        gemm_f32<<<ggrid, 256, 0, stream>>>(hin, Ws + (size_t)l * D * D, bufB, N);
        attn_scores<<<score_blocks, 256, 0, stream>>>(bufB, att_src + (size_t)l * H * C,
                                                      att_dst + (size_t)l * H * C, a_s, a_d, N);
        gat_aggregate<<<N, 256, 0, stream>>>(bufB, a_s, a_d, row_ptr, csr_src,
                                             biases + (size_t)l * D, bufA, N);
    }

    // ---- pool + head ----
    hipMemsetAsync(g, 0, D * 4, stream);
    int rows_per_blk = 100;
    col_sum<<<(N + rows_per_blk - 1) / rows_per_blk, 256, 0, stream>>>(bufA, g, N, rows_per_blk);
    final_kernel<<<1, 256, 0, stream>>>(g, Wout, bout, out, 1.0f / (float)N);
}

// Round 2
// 587.355 us; speedup vs baseline: 1.2051x; 1.2051x over previous
//
#include <hip/hip_runtime.h>
#include <hip/hip_bf16.h>

#define H 4
#define C 64
#define D 256
#define NEG_SLOPE 0.2f
#define LCAP 256

typedef __attribute__((ext_vector_type(8))) short short8v;
typedef __attribute__((ext_vector_type(4))) float f32x4;
typedef unsigned short ushort_t;

__device__ inline ushort_t f2bf(float f) {
    __hip_bfloat16 h = __float2bfloat16(f);
    return *reinterpret_cast<ushort_t*>(&h);
}
__device__ inline float bf2f(ushort_t u) {
    __hip_bfloat16 h = *reinterpret_cast<__hip_bfloat16*>(&u);
    return __bfloat162float(h);
}

// ---------------- CSR build ----------------
__global__ void count_kernel(const int* __restrict__ ei, int E, int N, int* __restrict__ counts) {
    int i = blockIdx.x * blockDim.x + threadIdx.x;
    if (i >= E + N) return;
    int d = (i < E) ? ei[E + i] : (i - E);
    atomicAdd(&counts[d], 1);
}

__global__ __launch_bounds__(1024) void prefix_scan(const int* __restrict__ counts,
                                                    int* __restrict__ row_ptr, int N) {
    __shared__ int buf[1024];
    __shared__ int carry_s;
    int tid = threadIdx.x;
    if (tid == 0) carry_s = 0;
    __syncthreads();
    for (int base = 0; base < N; base += 1024) {
        int idx = base + tid;
        int v = (idx < N) ? counts[idx] : 0;
        buf[tid] = v;
        __syncthreads();
        for (int offs = 1; offs < 1024; offs <<= 1) {
            int t = (tid >= offs) ? buf[tid - offs] : 0;
            __syncthreads();
            buf[tid] += t;
            __syncthreads();
        }
        int carry = carry_s;
        int incl = buf[tid];
        if (idx < N) row_ptr[idx] = carry + incl - v;
        __syncthreads();
        if (tid == 1023) carry_s = carry + incl;
        __syncthreads();
    }
    if (tid == 0) row_ptr[N] = carry_s;
}

__global__ void copy_cursor(const int* __restrict__ row_ptr, int* __restrict__ cursor, int N) {
    int i = blockIdx.x * blockDim.x + threadIdx.x;
    if (i < N) cursor[i] = row_ptr[i];
}

__global__ void scatter_kernel(const int* __restrict__ ei, int E, int N,
                               int* __restrict__ cursor, int* __restrict__ csr_src) {
    int i = blockIdx.x * blockDim.x + threadIdx.x;
    if (i >= E + N) return;
    int s, d;
    if (i < E) { s = ei[i]; d = ei[E + i]; }
    else       { s = d = i - E; }
    int pos = atomicAdd(&cursor[d], 1);
    csr_src[pos] = s;
}

// ---------------- fp32 -> bf16 hi/lo splits ----------------
__global__ void split_x(const float* __restrict__ in, ushort_t* __restrict__ hi,
                        ushort_t* __restrict__ lo, int n8) {
    int i = blockIdx.x * blockDim.x + threadIdx.x;
    if (i >= n8) return;
    float4 v0 = ((const float4*)in)[i * 2];
    float4 v1 = ((const float4*)in)[i * 2 + 1];
    float f[8] = {v0.x, v0.y, v0.z, v0.w, v1.x, v1.y, v1.z, v1.w};
    ushort_t hb[8] __attribute__((aligned(16)));
    ushort_t lb[8] __attribute__((aligned(16)));
    #pragma unroll
    for (int j = 0; j < 8; j++) {
        ushort_t h = f2bf(f[j]);
        hb[j] = h;
        lb[j] = f2bf(f[j] - bf2f(h));
    }
    ((uint4*)hi)[i] = *(uint4*)hb;
    ((uint4*)lo)[i] = *(uint4*)lb;
}

// W[l][k][col] -> Wt[l][col][k], split hi/lo
__global__ void split_w(const float* __restrict__ W, ushort_t* __restrict__ whi,
                        ushort_t* __restrict__ wlo, int total) {
    int i = blockIdx.x * blockDim.x + threadIdx.x;
    if (i >= total) return;
    int l = i >> 16;
    int rem = i & 65535;
    int col = rem >> 8;
    int k = rem & 255;
    float f = W[(l << 16) + (k << 8) + col];
    ushort_t h = f2bf(f);
    whi[i] = h;
    wlo[i] = f2bf(f - bf2f(h));
}

// ---------------- bf16x3 MFMA GEMM + fused attention scores ----------------
// grid: N/32 blocks, 128 threads (2 waves); wave covers 16 rows x 256 cols.
__global__ __launch_bounds__(128) void gemm_bf16x3(
    const ushort_t* __restrict__ Ahi, const ushort_t* __restrict__ Alo,
    const ushort_t* __restrict__ Wthi, const ushort_t* __restrict__ Wtlo,
    const float* __restrict__ asrc, const float* __restrict__ adst,
    float* __restrict__ hp, float* __restrict__ as_out, float* __restrict__ ad_out) {
    int wave = threadIdx.x >> 6, lane = threadIdx.x & 63;
    int r0 = blockIdx.x * 32 + wave * 16;
    int rlo = lane & 15;
    int khi = (lane >> 4) << 3;
    const ushort_t* pa_hi = Ahi + (r0 + rlo) * 256 + khi;
    const ushort_t* pa_lo = Alo + (r0 + rlo) * 256 + khi;
    const ushort_t* pb_hi = Wthi + rlo * 256 + khi;
    const ushort_t* pb_lo = Wtlo + rlo * 256 + khi;

    f32x4 acc[16];
    #pragma unroll
    for (int cb = 0; cb < 16; cb++) acc[cb] = (f32x4){0.f, 0.f, 0.f, 0.f};

    #pragma unroll 1
    for (int k0 = 0; k0 < 256; k0 += 32) {
        short8v ahi = *(const short8v*)(pa_hi + k0);
        short8v alo = *(const short8v*)(pa_lo + k0);
        #pragma unroll
        for (int cb = 0; cb < 16; cb++) {
            short8v bhi = *(const short8v*)(pb_hi + cb * 4096 + k0);
            short8v blo = *(const short8v*)(pb_lo + cb * 4096 + k0);
            acc[cb] = __builtin_amdgcn_mfma_f32_16x16x32_bf16(ahi, bhi, acc[cb], 0, 0, 0);
            acc[cb] = __builtin_amdgcn_mfma_f32_16x16x32_bf16(ahi, blo, acc[cb], 0, 0, 0);
            acc[cb] = __builtin_amdgcn_mfma_f32_16x16x32_bf16(alo, bhi, acc[cb], 0, 0, 0);
        }
    }

    // C/D layout: col = cb*16 + (lane&15), row = r0 + (lane>>4)*4 + i
    int rbase = r0 + ((lane >> 4) << 2);
    #pragma unroll
    for (int cb = 0; cb < 16; cb++) {
        #pragma unroll
        for (int i = 0; i < 4; i++)
            hp[(rbase + i) * 256 + cb * 16 + rlo] = acc[cb][i];
    }

    // fused a_s/a_d: per head, dot rows with att vectors
    #pragma unroll
    for (int h = 0; h < 4; h++) {
        float ps[4] = {0.f, 0.f, 0.f, 0.f};
        float pd[4] = {0.f, 0.f, 0.f, 0.f};
        #pragma unroll
        for (int cbl = 0; cbl < 4; cbl++) {
            int cb = h * 4 + cbl;
            float av = asrc[h * 64 + cbl * 16 + rlo];
            float dv = adst[h * 64 + cbl * 16 + rlo];
            #pragma unroll
            for (int i = 0; i < 4; i++) {
                ps[i] += acc[cb][i] * av;
                pd[i] += acc[cb][i] * dv;
            }
        }
        #pragma unroll
        for (int mask = 1; mask <= 8; mask <<= 1) {
            #pragma unroll
            for (int i = 0; i < 4; i++) {
                ps[i] += __shfl_xor(ps[i], mask);
                pd[i] += __shfl_xor(pd[i], mask);
            }
        }
        if (rlo == 0) {
            #pragma unroll
            for (int i = 0; i < 4; i++) {
                as_out[(rbase + i) * 4 + h] = ps[i];
                ad_out[(rbase + i) * 4 + h] = pd[i];
            }
        }
    }
}

// ---------------- GAT aggregation ----------------
// block per dst node, wave per head; LDS caches per-edge src + exp values.
__global__ __launch_bounds__(256) void gat_aggregate2(
    const float* __restrict__ hp, const float* __restrict__ as_, const float* __restrict__ ad_,
    const int* __restrict__ row_ptr, const int* __restrict__ csr_src,
    const float* __restrict__ bias, float* hf32,
    ushort_t* hhi, ushort_t* hlo, int write_f32) {
    __shared__ float lds_e[4][LCAP];
    __shared__ int   lds_s[4][LCAP];
    int d = blockIdx.x;
    int h = threadIdx.x >> 6, lane = threadIdx.x & 63;
    int r0 = row_ptr[d], deg = row_ptr[d + 1] - r0;
    float adv = ad_[d * 4 + h];
    float acc = 0.f, inv = 0.f;

    if (deg <= LCAP) {
        float m = -1e30f;
        for (int i = lane; i < deg; i += 64) {
            int s = csr_src[r0 + i];
            float e = as_[s * 4 + h] + adv;
            e = e > 0.f ? e : NEG_SLOPE * e;
            lds_s[h][i] = s;
            lds_e[h][i] = e;
            m = fmaxf(m, e);
        }
        #pragma unroll
        for (int o = 32; o; o >>= 1) m = fmaxf(m, __shfl_xor(m, o));
        float ssum = 0.f;
        for (int i = lane; i < deg; i += 64) {
            float ex = __expf(lds_e[h][i] - m);
            lds_e[h][i] = ex;
            ssum += ex;
        }
        #pragma unroll
        for (int o = 32; o; o >>= 1) ssum += __shfl_xor(ssum, o);
        inv = 1.0f / ssum;

        const float* hpb = hp + h * 64 + lane;
        int i = 0;
        for (; i + 2 <= deg; i += 2) {
            int s0 = lds_s[h][i], s1 = lds_s[h][i + 1];
            float a0 = lds_e[h][i], a1 = lds_e[h][i + 1];
            acc += a0 * hpb[s0 * 256];
            acc += a1 * hpb[s1 * 256];
        }
        if (i < deg) acc += lds_e[h][i] * hpb[lds_s[h][i] * 256];
    } else {
        // fallback: recompute path
        float m = -1e30f;
        for (int i = lane; i < deg; i += 64) {
            int s = csr_src[r0 + i];
            float e = as_[s * 4 + h] + adv;
            e = e > 0.f ? e : NEG_SLOPE * e;
            m = fmaxf(m, e);
        }
        #pragma unroll
        for (int o = 32; o; o >>= 1) m = fmaxf(m, __shfl_xor(m, o));
        float ssum = 0.f;
        for (int i = lane; i < deg; i += 64) {
            int s = csr_src[r0 + i];
            float e = as_[s * 4 + h] + adv;
            e = e > 0.f ? e : NEG_SLOPE * e;
            ssum += __expf(e - m);
        }
        #pragma unroll
        for (int o = 32; o; o >>= 1) ssum += __shfl_xor(ssum, o);
        inv = 1.0f / ssum;
        for (int i = 0; i < deg; i++) {
            int s = csr_src[r0 + i];
            float e = as_[s * 4 + h] + adv;
            e = e > 0.f ? e : NEG_SLOPE * e;
            acc += __expf(e - m) * hp[s * 256 + h * 64 + lane];
        }
    }

    float v = acc * inv + bias[h * 64 + lane];
    v = v > 0.f ? v : (__expf(v) - 1.0f);  // ELU
    int idx = d * 256 + h * 64 + lane;
    if (write_f32) {
        hf32[idx] = v;
    } else {
        ushort_t hb = f2bf(v);
        hhi[idx] = hb;
        hlo[idx] = f2bf(v - bf2f(hb));
    }
}

// ---------------- pooling + output head ----------------
__global__ __launch_bounds__(256) void col_sum(const float* __restrict__ hin,
                                               float* __restrict__ g, int N, int rows_per_blk) {
    int c = threadIdx.x;
    int r0 = blockIdx.x * rows_per_blk;
    int r1 = min(r0 + rows_per_blk, N);
    float acc = 0.f;
    for (int r = r0; r < r1; r++) acc += hin[r * D + c];
    atomicAdd(&g[c], acc);
}

__global__ __launch_bounds__(256) void final_kernel(const float* __restrict__ g,
                                                    const float* __restrict__ Wout,
                                                    const float* __restrict__ bout,
                                                    float* __restrict__ out, float invN) {
    int j = threadIdx.x;
    float acc = 0.f;
    for (int i = 0; i < D; i++) acc += g[i] * Wout[i * D + j];
    out[j] = acc * invN + bout[j];
}

extern "C" void kernel_launch(void* const* d_in, const int* in_sizes, int n_in,
                              void* d_out, int out_size, void* d_ws, size_t ws_size,
                              hipStream_t stream) {
    const float* x       = (const float*)d_in[0];
    const int*   ei      = (const int*)d_in[1];
    const float* Ws      = (const float*)d_in[2];
    const float* att_src = (const float*)d_in[3];
    const float* att_dst = (const float*)d_in[4];
    const float* biases  = (const float*)d_in[5];
    const float* Wout    = (const float*)d_in[6];
    const float* bout    = (const float*)d_in[7];
    float* out = (float*)d_out;

    int N = in_sizes[0] / D;          // 20000
    int E = in_sizes[1] / 2;          // 320000
    int L = in_sizes[2] / (D * D);    // 4
    int Etot = E + N;
    int Npad = (N + 63) & ~63;

    char* ws = (char*)d_ws;
    size_t off = 0;
    auto alloc = [&](size_t bytes) -> void* {
        void* p = ws + off;
        off = (off + bytes + 255) & ~(size_t)255;
        return p;
    };
    ushort_t* shi  = (ushort_t*)alloc((size_t)Npad * D * 2);
    ushort_t* slo  = (ushort_t*)alloc((size_t)Npad * D * 2);
    float* hp      = (float*)alloc((size_t)Npad * D * 4);
    float* a_s     = (float*)alloc((size_t)Npad * H * 4);
    float* a_d     = (float*)alloc((size_t)Npad * H * 4);
    ushort_t* wthi = (ushort_t*)alloc((size_t)L * D * D * 2);
    ushort_t* wtlo = (ushort_t*)alloc((size_t)L * D * D * 2);
    float* g       = (float*)alloc(D * 4);
    int*   counts  = (int*)alloc((size_t)N * 4);
    int*   row_ptr = (int*)alloc((size_t)(N + 1) * 4);
    int*   cursor  = (int*)alloc((size_t)N * 4);
    int*   csr_src = (int*)alloc((size_t)Etot * 4);
    float* hf32 = (float*)shi;   // last layer h (f32) aliases shi+slo (20.5MB = 2x10.26MB)
    if (off > ws_size) return;

    int thr = 256;

    // ---- splits ----
    int n8 = N * D / 8;
    split_x<<<(n8 + thr - 1) / thr, thr, 0, stream>>>(x, shi, slo, n8);
    int wtot = L * D * D;
    split_w<<<(wtot + thr - 1) / thr, thr, 0, stream>>>(Ws, wthi, wtlo, wtot);

    // ---- CSR build ----
    hipMemsetAsync(counts, 0, (size_t)N * 4, stream);
    count_kernel<<<(Etot + thr - 1) / thr, thr, 0, stream>>>(ei, E, N, counts);
    prefix_scan<<<1, 1024, 0, stream>>>(counts, row_ptr, N);
    copy_cursor<<<(N + thr - 1) / thr, thr, 0, stream>>>(row_ptr, cursor, N);
    scatter_kernel<<<(Etot + thr - 1) / thr, thr, 0, stream>>>(ei, E, N, cursor, csr_src);

    // ---- layers ----
    int gemm_blocks = (N + 31) / 32;
    for (int l = 0; l < L; l++) {
        gemm_bf16x3<<<gemm_blocks, 128, 0, stream>>>(
            shi, slo, wthi + (size_t)l * D * D, wtlo + (size_t)l * D * D,
            att_src + (size_t)l * H * C, att_dst + (size_t)l * H * C,
            hp, a_s, a_d);
        gat_aggregate2<<<N, 256, 0, stream>>>(
            hp, a_s, a_d, row_ptr, csr_src, biases + (size_t)l * D,
            hf32, shi, slo, (l == L - 1) ? 1 : 0);
    }

    // ---- pool + head ----
    hipMemsetAsync(g, 0, D * 4, stream);
    int rows_per_blk = 100;
    col_sum<<<(N + rows_per_blk - 1) / rows_per_blk, thr, 0, stream>>>(hf32, g, N, rows_per_blk);
    final_kernel<<<1, thr, 0, stream>>>(g, Wout, bout, out, 1.0f / (float)N);
}

// Round 3
// 511.579 us; speedup vs baseline: 1.3836x; 1.1481x over previous
//
#include <hip/hip_runtime.h>
#include <hip/hip_bf16.h>

#define H 4
#define C 64
#define D 256
#define NEG_SLOPE 0.2f
#define LCAP 256

typedef __attribute__((ext_vector_type(8))) short short8v;
typedef __attribute__((ext_vector_type(4))) float f32x4;
typedef unsigned short ushort_t;

__device__ inline ushort_t f2bf(float f) {
    __hip_bfloat16 h = __float2bfloat16(f);
    return *reinterpret_cast<ushort_t*>(&h);
}
__device__ inline float bf2f(ushort_t u) {
    __hip_bfloat16 h = *reinterpret_cast<__hip_bfloat16*>(&u);
    return __bfloat162float(h);
}

// ---------------- CSR build ----------------
__global__ void count_kernel(const int* __restrict__ ei, int E, int N, int* __restrict__ counts) {
    int i = blockIdx.x * blockDim.x + threadIdx.x;
    if (i >= E + N) return;
    int d = (i < E) ? ei[E + i] : (i - E);
    atomicAdd(&counts[d], 1);
}

__global__ __launch_bounds__(1024) void prefix_scan(const int* __restrict__ counts,
                                                    int* __restrict__ row_ptr, int N) {
    __shared__ int wsum[16];
    __shared__ int carry_s;
    int tid = threadIdx.x, lane = tid & 63, wid = tid >> 6;
    if (tid == 0) carry_s = 0;
    __syncthreads();
    for (int base = 0; base < N; base += 1024) {
        int idx = base + tid;
        int v = (idx < N) ? counts[idx] : 0;
        int val = v;
        #pragma unroll
        for (int o = 1; o < 64; o <<= 1) {
            int t = __shfl_up(val, o);
            if (lane >= o) val += t;
        }
        if (lane == 63) wsum[wid] = val;
        __syncthreads();
        int woff = 0;
        #pragma unroll
        for (int w = 0; w < 16; w++) woff += (w < wid) ? wsum[w] : 0;
        int carry = carry_s;
        if (idx < N) row_ptr[idx] = carry + woff + val - v;
        __syncthreads();
        if (tid == 1023) carry_s = carry + woff + val;
        __syncthreads();
    }
    if (threadIdx.x == 0) row_ptr[N] = carry_s;
}

__global__ void copy_cursor(const int* __restrict__ row_ptr, int* __restrict__ cursor, int N) {
    int i = blockIdx.x * blockDim.x + threadIdx.x;
    if (i < N) cursor[i] = row_ptr[i];
}

__global__ void scatter_kernel(const int* __restrict__ ei, int E, int N,
                               int* __restrict__ cursor, int* __restrict__ csr_src) {
    int i = blockIdx.x * blockDim.x + threadIdx.x;
    if (i >= E + N) return;
    int s, d;
    if (i < E) { s = ei[i]; d = ei[E + i]; }
    else       { s = d = i - E; }
    int pos = atomicAdd(&cursor[d], 1);
    csr_src[pos] = s;
}

// ---------------- fp32 -> bf16 hi/lo splits ----------------
__global__ void split_x(const float* __restrict__ in, ushort_t* __restrict__ hi,
                        ushort_t* __restrict__ lo, int n8) {
    int i = blockIdx.x * blockDim.x + threadIdx.x;
    if (i >= n8) return;
    float4 v0 = ((const float4*)in)[i * 2];
    float4 v1 = ((const float4*)in)[i * 2 + 1];
    float f[8] = {v0.x, v0.y, v0.z, v0.w, v1.x, v1.y, v1.z, v1.w};
    ushort_t hb[8] __attribute__((aligned(16)));
    ushort_t lb[8] __attribute__((aligned(16)));
    #pragma unroll
    for (int j = 0; j < 8; j++) {
        ushort_t h = f2bf(f[j]);
        hb[j] = h;
        lb[j] = f2bf(f[j] - bf2f(h));
    }
    ((uint4*)hi)[i] = *(uint4*)hb;
    ((uint4*)lo)[i] = *(uint4*)lb;
}

// W[l][k][col] -> Wt[l][col][k], split hi/lo
__global__ void split_w(const float* __restrict__ W, ushort_t* __restrict__ whi,
                        ushort_t* __restrict__ wlo, int total) {
    int i = blockIdx.x * blockDim.x + threadIdx.x;
    if (i >= total) return;
    int l = i >> 16;
    int rem = i & 65535;
    int col = rem >> 8;
    int k = rem & 255;
    float f = W[(l << 16) + (k << 8) + col];
    ushort_t h = f2bf(f);
    whi[i] = h;
    wlo[i] = f2bf(f - bf2f(h));
}

// ---------------- bf16x3 MFMA GEMM + fused attention scores ----------------
// block: 256 thr = 4 waves; wave = 16 rows x 128 cols; block = 32 rows x 256 cols.
__global__ __launch_bounds__(256) void gemm_bf16x3(
    const ushort_t* __restrict__ Ahi, const ushort_t* __restrict__ Alo,
    const ushort_t* __restrict__ Wthi, const ushort_t* __restrict__ Wtlo,
    const float* __restrict__ asrc, const float* __restrict__ adst,
    ushort_t* __restrict__ hp, float* __restrict__ as_out, float* __restrict__ ad_out) {
    int wave = threadIdx.x >> 6, lane = threadIdx.x & 63;
    int rsub = wave >> 1;          // row subtile 0..1
    int csub = wave & 1;           // col half 0..1
    int r0 = blockIdx.x * 32 + rsub * 16;
    int rlo = lane & 15;
    int khi = (lane >> 4) << 3;
    const ushort_t* pa_hi = Ahi + (size_t)(r0 + rlo) * 256 + khi;
    const ushort_t* pa_lo = Alo + (size_t)(r0 + rlo) * 256 + khi;
    const ushort_t* pb_hi = Wthi + (size_t)(csub * 128 + rlo) * 256 + khi;
    const ushort_t* pb_lo = Wtlo + (size_t)(csub * 128 + rlo) * 256 + khi;

    f32x4 acc[8];
    #pragma unroll
    for (int cb = 0; cb < 8; cb++) acc[cb] = (f32x4){0.f, 0.f, 0.f, 0.f};

    #pragma unroll 2
    for (int k0 = 0; k0 < 256; k0 += 32) {
        short8v ahi = *(const short8v*)(pa_hi + k0);
        short8v alo = *(const short8v*)(pa_lo + k0);
        #pragma unroll
        for (int cb = 0; cb < 8; cb++) {
            short8v bhi = *(const short8v*)(pb_hi + cb * 4096 + k0);
            short8v blo = *(const short8v*)(pb_lo + cb * 4096 + k0);
            acc[cb] = __builtin_amdgcn_mfma_f32_16x16x32_bf16(ahi, bhi, acc[cb], 0, 0, 0);
            acc[cb] = __builtin_amdgcn_mfma_f32_16x16x32_bf16(ahi, blo, acc[cb], 0, 0, 0);
            acc[cb] = __builtin_amdgcn_mfma_f32_16x16x32_bf16(alo, bhi, acc[cb], 0, 0, 0);
        }
    }

    // C/D layout: col = csub*128 + cb*16 + rlo, row = r0 + (lane>>4)*4 + i
    int rbase = r0 + ((lane >> 4) << 2);
    #pragma unroll
    for (int cb = 0; cb < 8; cb++) {
        #pragma unroll
        for (int i = 0; i < 4; i++)
            hp[(size_t)(rbase + i) * 256 + csub * 128 + cb * 16 + rlo] = f2bf(acc[cb][i]);
    }

    // fused a_s/a_d: this wave's col half covers heads {2*csub, 2*csub+1}
    #pragma unroll
    for (int hl = 0; hl < 2; hl++) {
        int h = csub * 2 + hl;
        float ps[4] = {0.f, 0.f, 0.f, 0.f};
        float pd[4] = {0.f, 0.f, 0.f, 0.f};
        #pragma unroll
        for (int cbl = 0; cbl < 4; cbl++) {
            int cb = hl * 4 + cbl;
            float av = asrc[h * 64 + cbl * 16 + rlo];
            float dv = adst[h * 64 + cbl * 16 + rlo];
            #pragma unroll
            for (int i = 0; i < 4; i++) {
                ps[i] += acc[cb][i] * av;
                pd[i] += acc[cb][i] * dv;
            }
        }
        #pragma unroll
        for (int mask = 1; mask <= 8; mask <<= 1) {
            #pragma unroll
            for (int i = 0; i < 4; i++) {
                ps[i] += __shfl_xor(ps[i], mask);
                pd[i] += __shfl_xor(pd[i], mask);
            }
        }
        if (rlo == 0) {
            #pragma unroll
            for (int i = 0; i < 4; i++) {
                as_out[(size_t)(rbase + i) * 4 + h] = ps[i];
                ad_out[(size_t)(rbase + i) * 4 + h] = pd[i];
            }
        }
    }
}

// ---------------- GAT aggregation (bf16 hp gather) ----------------
__global__ __launch_bounds__(256) void gat_aggregate2(
    const ushort_t* __restrict__ hp, const float* __restrict__ as_, const float* __restrict__ ad_,
    const int* __restrict__ row_ptr, const int* __restrict__ csr_src,
    const float* __restrict__ bias, float* hf32,
    ushort_t* hhi, ushort_t* hlo, int write_f32) {
    __shared__ float lds_e[4][LCAP];
    __shared__ int   lds_s[4][LCAP];
    int d = blockIdx.x;
    int h = threadIdx.x >> 6, lane = threadIdx.x & 63;
    int r0 = row_ptr[d], deg = row_ptr[d + 1] - r0;
    float adv = ad_[d * 4 + h];
    float acc = 0.f, inv = 0.f;

    if (deg <= LCAP) {
        float m = -1e30f;
        for (int i = lane; i < deg; i += 64) {
            int s = csr_src[r0 + i];
            float e = as_[s * 4 + h] + adv;
            e = e > 0.f ? e : NEG_SLOPE * e;
            lds_s[h][i] = s;
            lds_e[h][i] = e;
            m = fmaxf(m, e);
        }
        #pragma unroll
        for (int o = 32; o; o >>= 1) m = fmaxf(m, __shfl_xor(m, o));
        float ssum = 0.f;
        for (int i = lane; i < deg; i += 64) {
            float ex = __expf(lds_e[h][i] - m);
            lds_e[h][i] = ex;
            ssum += ex;
        }
        #pragma unroll
        for (int o = 32; o; o >>= 1) ssum += __shfl_xor(ssum, o);
        inv = 1.0f / ssum;

        const ushort_t* hpb = hp + h * 64 + lane;
        int i = 0;
        for (; i + 4 <= deg; i += 4) {
            int s0 = lds_s[h][i],     s1 = lds_s[h][i + 1];
            int s2 = lds_s[h][i + 2], s3 = lds_s[h][i + 3];
            float a0 = lds_e[h][i],     a1 = lds_e[h][i + 1];
            float a2 = lds_e[h][i + 2], a3 = lds_e[h][i + 3];
            float v0 = bf2f(hpb[(size_t)s0 * 256]);
            float v1 = bf2f(hpb[(size_t)s1 * 256]);
            float v2 = bf2f(hpb[(size_t)s2 * 256]);
            float v3 = bf2f(hpb[(size_t)s3 * 256]);
            acc += a0 * v0 + a1 * v1 + a2 * v2 + a3 * v3;
        }
        for (; i < deg; i++)
            acc += lds_e[h][i] * bf2f(hpb[(size_t)lds_s[h][i] * 256]);
    } else {
        // fallback: recompute path
        float m = -1e30f;
        for (int i = lane; i < deg; i += 64) {
            int s = csr_src[r0 + i];
            float e = as_[s * 4 + h] + adv;
            e = e > 0.f ? e : NEG_SLOPE * e;
            m = fmaxf(m, e);
        }
        #pragma unroll
        for (int o = 32; o; o >>= 1) m = fmaxf(m, __shfl_xor(m, o));
        float ssum = 0.f;
        for (int i = lane; i < deg; i += 64) {
            int s = csr_src[r0 + i];
            float e = as_[s * 4 + h] + adv;
            e = e > 0.f ? e : NEG_SLOPE * e;
            ssum += __expf(e - m);
        }
        #pragma unroll
        for (int o = 32; o; o >>= 1) ssum += __shfl_xor(ssum, o);
        inv = 1.0f / ssum;
        for (int i = 0; i < deg; i++) {
            int s = csr_src[r0 + i];
            float e = as_[s * 4 + h] + adv;
            e = e > 0.f ? e : NEG_SLOPE * e;
            acc += __expf(e - m) * bf2f(hp[(size_t)s * 256 + h * 64 + lane]);
        }
    }

    float v = acc * inv + bias[h * 64 + lane];
    v = v > 0.f ? v : (__expf(v) - 1.0f);  // ELU
    size_t idx = (size_t)d * 256 + h * 64 + lane;
    if (write_f32) {
        hf32[idx] = v;
    } else {
        ushort_t hb = f2bf(v);
        hhi[idx] = hb;
        hlo[idx] = f2bf(v - bf2f(hb));
    }
}

// ---------------- pooling + output head ----------------
__global__ __launch_bounds__(256) void col_sum(const float* __restrict__ hin,
                                               float* __restrict__ g, int N, int rows_per_blk) {
    int c = threadIdx.x;
    int r0 = blockIdx.x * rows_per_blk;
    int r1 = min(r0 + rows_per_blk, N);
    float acc = 0.f;
    for (int r = r0; r < r1; r++) acc += hin[(size_t)r * D + c];
    atomicAdd(&g[c], acc);
}

__global__ __launch_bounds__(256) void final_kernel(const float* __restrict__ g,
                                                    const float* __restrict__ Wout,
                                                    const float* __restrict__ bout,
                                                    float* __restrict__ out, float invN) {
    int j = threadIdx.x;
    float acc = 0.f;
    for (int i = 0; i < D; i++) acc += g[i] * Wout[i * D + j];
    out[j] = acc * invN + bout[j];
}

extern "C" void kernel_launch(void* const* d_in, const int* in_sizes, int n_in,
                              void* d_out, int out_size, void* d_ws, size_t ws_size,
                              hipStream_t stream) {
    const float* x       = (const float*)d_in[0];
    const int*   ei      = (const int*)d_in[1];
    const float* Ws      = (const float*)d_in[2];
    const float* att_src = (const float*)d_in[3];
    const float* att_dst = (const float*)d_in[4];
    const float* biases  = (const float*)d_in[5];
    const float* Wout    = (const float*)d_in[6];
    const float* bout    = (const float*)d_in[7];
    float* out = (float*)d_out;

    int N = in_sizes[0] / D;          // 20000
    int E = in_sizes[1] / 2;          // 320000
    int L = in_sizes[2] / (D * D);    // 4
    int Etot = E + N;
    int Npad = (N + 63) & ~63;

    char* ws = (char*)d_ws;
    size_t off = 0;
    auto alloc = [&](size_t bytes) -> void* {
        void* p = ws + off;
        off = (off + bytes + 255) & ~(size_t)255;
        return p;
    };
    ushort_t* shi  = (ushort_t*)alloc((size_t)Npad * D * 2);
    ushort_t* slo  = (ushort_t*)alloc((size_t)Npad * D * 2);
    ushort_t* hp   = (ushort_t*)alloc((size_t)Npad * D * 2);
    float* a_s     = (float*)alloc((size_t)Npad * H * 4);
    float* a_d     = (float*)alloc((size_t)Npad * H * 4);
    ushort_t* wthi = (ushort_t*)alloc((size_t)L * D * D * 2);
    ushort_t* wtlo = (ushort_t*)alloc((size_t)L * D * D * 2);
    float* g       = (float*)alloc(D * 4);
    int*   counts  = (int*)alloc((size_t)N * 4);
    int*   row_ptr = (int*)alloc((size_t)(N + 1) * 4);
    int*   cursor  = (int*)alloc((size_t)N * 4);
    int*   csr_src = (int*)alloc((size_t)Etot * 4);
    float* hf32 = (float*)shi;   // last-layer h (f32) aliases shi+slo (contiguous, 2x bf16 = f32 size)
    if (off > ws_size) return;

    int thr = 256;

    // ---- splits ----
    int n8 = N * D / 8;
    split_x<<<(n8 + thr - 1) / thr, thr, 0, stream>>>(x, shi, slo, n8);
    int wtot = L * D * D;
    split_w<<<(wtot + thr - 1) / thr, thr, 0, stream>>>(Ws, wthi, wtlo, wtot);

    // ---- CSR build ----
    hipMemsetAsync(counts, 0, (size_t)N * 4, stream);
    count_kernel<<<(Etot + thr - 1) / thr, thr, 0, stream>>>(ei, E, N, counts);
    prefix_scan<<<1, 1024, 0, stream>>>(counts, row_ptr, N);
    copy_cursor<<<(N + thr - 1) / thr, thr, 0, stream>>>(row_ptr, cursor, N);
    scatter_kernel<<<(Etot + thr - 1) / thr, thr, 0, stream>>>(ei, E, N, cursor, csr_src);

    // ---- layers ----
    int gemm_blocks = (N + 31) / 32;
    for (int l = 0; l < L; l++) {
        gemm_bf16x3<<<gemm_blocks, 256, 0, stream>>>(
            shi, slo, wthi + (size_t)l * D * D, wtlo + (size_t)l * D * D,
            att_src + (size_t)l * H * C, att_dst + (size_t)l * H * C,
            hp, a_s, a_d);
        gat_aggregate2<<<N, 256, 0, stream>>>(
            hp, a_s, a_d, row_ptr, csr_src, biases + (size_t)l * D,
            hf32, shi, slo, (l == L - 1) ? 1 : 0);
    }

    // ---- pool + head ----
    hipMemsetAsync(g, 0, D * 4, stream);
    int rows_per_blk = 100;
    col_sum<<<(N + rows_per_blk - 1) / rows_per_blk, thr, 0, stream>>>(hf32, g, N, rows_per_blk);
    final_kernel<<<1, thr, 0, stream>>>(g, Wout, bout, out, 1.0f / (float)N);
}

// Round 4
// 450.242 us; speedup vs baseline: 1.5721x; 1.1362x over previous
//
#include <hip/hip_runtime.h>
#include <hip/hip_bf16.h>

#define H 4
#define C 64
#define D 256
#define NEG_SLOPE 0.2f
#define LCAP 256

typedef __attribute__((ext_vector_type(8))) short short8v;
typedef __attribute__((ext_vector_type(4))) float f32x4;
typedef unsigned short ushort_t;

__device__ inline ushort_t f2bf(float f) {
    __hip_bfloat16 h = __float2bfloat16(f);
    return *reinterpret_cast<ushort_t*>(&h);
}
__device__ inline float bf2f(ushort_t u) {
    __hip_bfloat16 h = *reinterpret_cast<__hip_bfloat16*>(&u);
    return __bfloat162float(h);
}

// ---------------- CSR build ----------------
__global__ void count_kernel(const int* __restrict__ ei, int E, int N, int* __restrict__ counts) {
    int i = blockIdx.x * blockDim.x + threadIdx.x;
    if (i >= E + N) return;
    int d = (i < E) ? ei[E + i] : (i - E);
    atomicAdd(&counts[d], 1);
}

__global__ __launch_bounds__(1024) void prefix_scan(const int* __restrict__ counts,
                                                    int* __restrict__ row_ptr, int N) {
    __shared__ int wsum[16];
    __shared__ int carry_s;
    int tid = threadIdx.x, lane = tid & 63, wid = tid >> 6;
    if (tid == 0) carry_s = 0;
    __syncthreads();
    for (int base = 0; base < N; base += 1024) {
        int idx = base + tid;
        int v = (idx < N) ? counts[idx] : 0;
        int val = v;
        #pragma unroll
        for (int o = 1; o < 64; o <<= 1) {
            int t = __shfl_up(val, o);
            if (lane >= o) val += t;
        }
        if (lane == 63) wsum[wid] = val;
        __syncthreads();
        int woff = 0;
        #pragma unroll
        for (int w = 0; w < 16; w++) woff += (w < wid) ? wsum[w] : 0;
        int carry = carry_s;
        if (idx < N) row_ptr[idx] = carry + woff + val - v;
        __syncthreads();
        if (tid == 1023) carry_s = carry + woff + val;
        __syncthreads();
    }
    if (threadIdx.x == 0) row_ptr[N] = carry_s;
}

__global__ void copy_cursor(const int* __restrict__ row_ptr, int* __restrict__ cursor, int N) {
    int i = blockIdx.x * blockDim.x + threadIdx.x;
    if (i < N) cursor[i] = row_ptr[i];
}

__global__ void scatter_kernel(const int* __restrict__ ei, int E, int N,
                               int* __restrict__ cursor, int* __restrict__ csr_src) {
    int i = blockIdx.x * blockDim.x + threadIdx.x;
    if (i >= E + N) return;
    int s, d;
    if (i < E) { s = ei[i]; d = ei[E + i]; }
    else       { s = d = i - E; }
    int pos = atomicAdd(&cursor[d], 1);
    csr_src[pos] = s;
}

// ---------------- fp32 -> bf16 hi/lo splits ----------------
__global__ void split_x(const float* __restrict__ in, ushort_t* __restrict__ hi,
                        ushort_t* __restrict__ lo, int n8) {
    int i = blockIdx.x * blockDim.x + threadIdx.x;
    if (i >= n8) return;
    float4 v0 = ((const float4*)in)[i * 2];
    float4 v1 = ((const float4*)in)[i * 2 + 1];
    float f[8] = {v0.x, v0.y, v0.z, v0.w, v1.x, v1.y, v1.z, v1.w};
    ushort_t hb[8] __attribute__((aligned(16)));
    ushort_t lb[8] __attribute__((aligned(16)));
    #pragma unroll
    for (int j = 0; j < 8; j++) {
        ushort_t h = f2bf(f[j]);
        hb[j] = h;
        lb[j] = f2bf(f[j] - bf2f(h));
    }
    ((uint4*)hi)[i] = *(uint4*)hb;
    ((uint4*)lo)[i] = *(uint4*)lb;
}

// W[l][k][col] -> Wt[l][col][k], split hi/lo
__global__ void split_w(const float* __restrict__ W, ushort_t* __restrict__ whi,
                        ushort_t* __restrict__ wlo, int total) {
    int i = blockIdx.x * blockDim.x + threadIdx.x;
    if (i >= total) return;
    int l = i >> 16;
    int rem = i & 65535;
    int col = rem >> 8;
    int k = rem & 255;
    float f = W[(l << 16) + (k << 8) + col];
    ushort_t h = f2bf(f);
    whi[i] = h;
    wlo[i] = f2bf(f - bf2f(h));
}

// ---------------- bf16x3 MFMA GEMM + fused attention scores ----------------
// block: 256 thr = 4 waves; wave = 32 rows x 64 cols (one head); block = 32 rows x 256 cols.
__global__ __launch_bounds__(256) void gemm_bf16x3(
    const ushort_t* __restrict__ Ahi, const ushort_t* __restrict__ Alo,
    const ushort_t* __restrict__ Wthi, const ushort_t* __restrict__ Wtlo,
    const float* __restrict__ asrc, const float* __restrict__ adst,
    ushort_t* __restrict__ hp, float* __restrict__ as_out, float* __restrict__ ad_out) {
    int wave = threadIdx.x >> 6, lane = threadIdx.x & 63;
    int h = wave;                  // col quarter == head
    int r0 = blockIdx.x * 32;
    int rlo = lane & 15;
    int khi = (lane >> 4) << 3;
    const ushort_t* pa_hi0 = Ahi + (size_t)(r0 + rlo) * 256 + khi;
    const ushort_t* pa_lo0 = Alo + (size_t)(r0 + rlo) * 256 + khi;
    const ushort_t* pa_hi1 = pa_hi0 + 16 * 256;
    const ushort_t* pa_lo1 = pa_lo0 + 16 * 256;
    const ushort_t* pb_hi = Wthi + (size_t)(h * 64 + rlo) * 256 + khi;
    const ushort_t* pb_lo = Wtlo + (size_t)(h * 64 + rlo) * 256 + khi;

    f32x4 acc[2][4];
    #pragma unroll
    for (int rf = 0; rf < 2; rf++)
        #pragma unroll
        for (int cb = 0; cb < 4; cb++) acc[rf][cb] = (f32x4){0.f, 0.f, 0.f, 0.f};

    #pragma unroll 2
    for (int k0 = 0; k0 < 256; k0 += 32) {
        short8v ahi0 = *(const short8v*)(pa_hi0 + k0);
        short8v alo0 = *(const short8v*)(pa_lo0 + k0);
        short8v ahi1 = *(const short8v*)(pa_hi1 + k0);
        short8v alo1 = *(const short8v*)(pa_lo1 + k0);
        #pragma unroll
        for (int cb = 0; cb < 4; cb++) {
            short8v bhi = *(const short8v*)(pb_hi + cb * 4096 + k0);
            short8v blo = *(const short8v*)(pb_lo + cb * 4096 + k0);
            acc[0][cb] = __builtin_amdgcn_mfma_f32_16x16x32_bf16(ahi0, bhi, acc[0][cb], 0, 0, 0);
            acc[0][cb] = __builtin_amdgcn_mfma_f32_16x16x32_bf16(ahi0, blo, acc[0][cb], 0, 0, 0);
            acc[0][cb] = __builtin_amdgcn_mfma_f32_16x16x32_bf16(alo0, bhi, acc[0][cb], 0, 0, 0);
            acc[1][cb] = __builtin_amdgcn_mfma_f32_16x16x32_bf16(ahi1, bhi, acc[1][cb], 0, 0, 0);
            acc[1][cb] = __builtin_amdgcn_mfma_f32_16x16x32_bf16(ahi1, blo, acc[1][cb], 0, 0, 0);
            acc[1][cb] = __builtin_amdgcn_mfma_f32_16x16x32_bf16(alo1, bhi, acc[1][cb], 0, 0, 0);
        }
    }

    // C/D layout: col = h*64 + cb*16 + rlo, row = r0 + rf*16 + (lane>>4)*4 + i
    #pragma unroll
    for (int rf = 0; rf < 2; rf++) {
        int rbase = r0 + rf * 16 + ((lane >> 4) << 2);
        #pragma unroll
        for (int cb = 0; cb < 4; cb++) {
            #pragma unroll
            for (int i = 0; i < 4; i++)
                hp[(size_t)(rbase + i) * 256 + h * 64 + cb * 16 + rlo] = f2bf(acc[rf][cb][i]);
        }
    }

    // fused a_s/a_d for this wave's head
    #pragma unroll
    for (int rf = 0; rf < 2; rf++) {
        float ps[4] = {0.f, 0.f, 0.f, 0.f};
        float pd[4] = {0.f, 0.f, 0.f, 0.f};
        #pragma unroll
        for (int cb = 0; cb < 4; cb++) {
            float av = asrc[h * 64 + cb * 16 + rlo];
            float dv = adst[h * 64 + cb * 16 + rlo];
            #pragma unroll
            for (int i = 0; i < 4; i++) {
                ps[i] += acc[rf][cb][i] * av;
                pd[i] += acc[rf][cb][i] * dv;
            }
        }
        #pragma unroll
        for (int mask = 1; mask <= 8; mask <<= 1) {
            #pragma unroll
            for (int i = 0; i < 4; i++) {
                ps[i] += __shfl_xor(ps[i], mask);
                pd[i] += __shfl_xor(pd[i], mask);
            }
        }
        if (rlo == 0) {
            int rbase = r0 + rf * 16 + ((lane >> 4) << 2);
            #pragma unroll
            for (int i = 0; i < 4; i++) {
                as_out[(size_t)(rbase + i) * 4 + h] = ps[i];
                ad_out[(size_t)(rbase + i) * 4 + h] = pd[i];
            }
        }
    }
}

// ---------------- GAT aggregation (bf16 hp gather) ----------------
__global__ __launch_bounds__(256) void gat_aggregate2(
    const ushort_t* __restrict__ hp, const float* __restrict__ as_, const float* __restrict__ ad_,
    const int* __restrict__ row_ptr, const int* __restrict__ csr_src,
    const float* __restrict__ bias, float* hf32,
    ushort_t* hhi, ushort_t* hlo, int write_f32) {
    __shared__ float lds_e[4][LCAP];
    __shared__ int   lds_s[4][LCAP];
    int d = blockIdx.x;
    int h = threadIdx.x >> 6, lane = threadIdx.x & 63;
    int r0 = row_ptr[d], deg = row_ptr[d + 1] - r0;
    float adv = ad_[d * 4 + h];
    float acc = 0.f, inv = 0.f;

    if (deg <= LCAP) {
        float m = -1e30f;
        for (int i = lane; i < deg; i += 64) {
            int s = csr_src[r0 + i];
            float e = as_[s * 4 + h] + adv;
            e = e > 0.f ? e : NEG_SLOPE * e;
            lds_s[h][i] = s;
            lds_e[h][i] = e;
            m = fmaxf(m, e);
        }
        #pragma unroll
        for (int o = 32; o; o >>= 1) m = fmaxf(m, __shfl_xor(m, o));
        float ssum = 0.f;
        for (int i = lane; i < deg; i += 64) {
            float ex = __expf(lds_e[h][i] - m);
            lds_e[h][i] = ex;
            ssum += ex;
        }
        #pragma unroll
        for (int o = 32; o; o >>= 1) ssum += __shfl_xor(ssum, o);
        inv = 1.0f / ssum;

        const ushort_t* hpb = hp + h * 64 + lane;
        int i = 0;
        for (; i + 4 <= deg; i += 4) {
            int s0 = lds_s[h][i],     s1 = lds_s[h][i + 1];
            int s2 = lds_s[h][i + 2], s3 = lds_s[h][i + 3];
            float a0 = lds_e[h][i],     a1 = lds_e[h][i + 1];
            float a2 = lds_e[h][i + 2], a3 = lds_e[h][i + 3];
            float v0 = bf2f(hpb[(size_t)s0 * 256]);
            float v1 = bf2f(hpb[(size_t)s1 * 256]);
            float v2 = bf2f(hpb[(size_t)s2 * 256]);
            float v3 = bf2f(hpb[(size_t)s3 * 256]);
            acc += a0 * v0 + a1 * v1 + a2 * v2 + a3 * v3;
        }
        for (; i < deg; i++)
            acc += lds_e[h][i] * bf2f(hpb[(size_t)lds_s[h][i] * 256]);
    } else {
        // fallback: recompute path
        float m = -1e30f;
        for (int i = lane; i < deg; i += 64) {
            int s = csr_src[r0 + i];
            float e = as_[s * 4 + h] + adv;
            e = e > 0.f ? e : NEG_SLOPE * e;
            m = fmaxf(m, e);
        }
        #pragma unroll
        for (int o = 32; o; o >>= 1) m = fmaxf(m, __shfl_xor(m, o));
        float ssum = 0.f;
        for (int i = lane; i < deg; i += 64) {
            int s = csr_src[r0 + i];
            float e = as_[s * 4 + h] + adv;
            e = e > 0.f ? e : NEG_SLOPE * e;
            ssum += __expf(e - m);
        }
        #pragma unroll
        for (int o = 32; o; o >>= 1) ssum += __shfl_xor(ssum, o);
        inv = 1.0f / ssum;
        for (int i = 0; i < deg; i++) {
            int s = csr_src[r0 + i];
            float e = as_[s * 4 + h] + adv;
            e = e > 0.f ? e : NEG_SLOPE * e;
            acc += __expf(e - m) * bf2f(hp[(size_t)s * 256 + h * 64 + lane]);
        }
    }

    float v = acc * inv + bias[h * 64 + lane];
    v = v > 0.f ? v : (__expf(v) - 1.0f);  // ELU
    size_t idx = (size_t)d * 256 + h * 64 + lane;
    if (write_f32) {
        hf32[idx] = v;
    } else {
        ushort_t hb = f2bf(v);
        hhi[idx] = hb;
        hlo[idx] = f2bf(v - bf2f(hb));
    }
}

// ---------------- pooling + output head ----------------
__global__ __launch_bounds__(256) void col_sum(const float* __restrict__ hin,
                                               float* __restrict__ g, int N, int rows_per_blk) {
    int c = threadIdx.x;
    int r0 = blockIdx.x * rows_per_blk;
    int r1 = min(r0 + rows_per_blk, N);
    float acc = 0.f;
    for (int r = r0; r < r1; r++) acc += hin[(size_t)r * D + c];
    atomicAdd(&g[c], acc);
}

__global__ __launch_bounds__(256) void final_kernel(const float* __restrict__ g,
                                                    const float* __restrict__ Wout,
                                                    const float* __restrict__ bout,
                                                    float* __restrict__ out, float invN) {
    int j = threadIdx.x;
    float acc = 0.f;
    for (int i = 0; i < D; i++) acc += g[i] * Wout[i * D + j];
    out[j] = acc * invN + bout[j];
}

extern "C" void kernel_launch(void* const* d_in, const int* in_sizes, int n_in,
                              void* d_out, int out_size, void* d_ws, size_t ws_size,
                              hipStream_t stream) {
    const float* x       = (const float*)d_in[0];
    const int*   ei      = (const int*)d_in[1];
    const float* Ws      = (const float*)d_in[2];
    const float* att_src = (const float*)d_in[3];
    const float* att_dst = (const float*)d_in[4];
    const float* biases  = (const float*)d_in[5];
    const float* Wout    = (const float*)d_in[6];
    const float* bout    = (const float*)d_in[7];
    float* out = (float*)d_out;

    int N = in_sizes[0] / D;          // 20000
    int E = in_sizes[1] / 2;          // 320000
    int L = in_sizes[2] / (D * D);    // 4
    int Etot = E + N;
    int Npad = (N + 63) & ~63;

    char* ws = (char*)d_ws;
    size_t off = 0;
    auto alloc = [&](size_t bytes) -> void* {
        void* p = ws + off;
        off = (off + bytes + 255) & ~(size_t)255;
        return p;
    };
    ushort_t* shi  = (ushort_t*)alloc((size_t)Npad * D * 2);
    ushort_t* slo  = (ushort_t*)alloc((size_t)Npad * D * 2);
    ushort_t* hp   = (ushort_t*)alloc((size_t)Npad * D * 2);
    float* a_s     = (float*)alloc((size_t)Npad * H * 4);
    float* a_d     = (float*)alloc((size_t)Npad * H * 4);
    ushort_t* wthi = (ushort_t*)alloc((size_t)L * D * D * 2);
    ushort_t* wtlo = (ushort_t*)alloc((size_t)L * D * D * 2);
    float* g       = (float*)alloc(D * 4);
    int*   counts  = (int*)alloc((size_t)N * 4);
    int*   row_ptr = (int*)alloc((size_t)(N + 1) * 4);
    int*   cursor  = (int*)alloc((size_t)N * 4);
    int*   csr_src = (int*)alloc((size_t)Etot * 4);
    float* hf32 = (float*)shi;   // last-layer h (f32) aliases shi+slo (contiguous, 2x bf16 = f32 size)
    if (off > ws_size) return;

    int thr = 256;

    // ---- splits ----
    int n8 = N * D / 8;
    split_x<<<(n8 + thr - 1) / thr, thr, 0, stream>>>(x, shi, slo, n8);
    int wtot = L * D * D;
    split_w<<<(wtot + thr - 1) / thr, thr, 0, stream>>>(Ws, wthi, wtlo, wtot);

    // ---- CSR build ----
    hipMemsetAsync(counts, 0, (size_t)N * 4, stream);
    count_kernel<<<(Etot + thr - 1) / thr, thr, 0, stream>>>(ei, E, N, counts);
    prefix_scan<<<1, 1024, 0, stream>>>(counts, row_ptr, N);
    copy_cursor<<<(N + thr - 1) / thr, thr, 0, stream>>>(row_ptr, cursor, N);
    scatter_kernel<<<(Etot + thr - 1) / thr, thr, 0, stream>>>(ei, E, N, cursor, csr_src);

    // ---- layers ----
    int gemm_blocks = (N + 31) / 32;
    for (int l = 0; l < L; l++) {
        gemm_bf16x3<<<gemm_blocks, 256, 0, stream>>>(
            shi, slo, wthi + (size_t)l * D * D, wtlo + (size_t)l * D * D,
            att_src + (size_t)l * H * C, att_dst + (size_t)l * H * C,
            hp, a_s, a_d);
        gat_aggregate2<<<N, 256, 0, stream>>>(
            hp, a_s, a_d, row_ptr, csr_src, biases + (size_t)l * D,
            hf32, shi, slo, (l == L - 1) ? 1 : 0);
    }

    // ---- pool + head ----
    hipMemsetAsync(g, 0, D * 4, stream);
    int rows_per_blk = 100;
    col_sum<<<(N + rows_per_blk - 1) / rows_per_blk, thr, 0, stream>>>(hf32, g, N, rows_per_blk);
    final_kernel<<<1, thr, 0, stream>>>(g, Wout, bout, out, 1.0f / (float)N);
}